// Round 10
// baseline (4907.044 us; speedup 1.0000x reference)
//
#include <hip/hip_runtime.h>

typedef _Float16 h16;
typedef __attribute__((ext_vector_type(8))) _Float16 half8;
typedef __attribute__((ext_vector_type(4))) float f32x4;
typedef __attribute__((ext_vector_type(4))) unsigned u32x4;
typedef unsigned long long ull;

#define B_   1024
#define T_   256
#define D_   128
#define H_   512
#define Kc_  640    // D + H
#define NR_  2048   // 4H rows, R-mapped
#define AGENT_ __HIP_MEMORY_SCOPE_AGENT

__device__ __forceinline__ float sigm_(float v) {
    return 1.0f / (1.0f + __expf(-v));
}
__device__ __forceinline__ float tanh_(float v) {
    v = fminf(15.0f, fmaxf(-15.0f, v));
    const float e = __expf(2.0f * v);
    return (e - 1.0f) / (e + 1.0f);
}

// Raw MFMA: acc(VGPR) += W(AGPR) * B(VGPR). A-operand straight from AGPRs —
// no v_accvgpr_read moves, and the asm is opaque so W can't be rematerialized.
#define MFMA_A(acc, w, b) \
    asm volatile("v_mfma_f32_16x16x32_f16 %0, %1, %2, %0" \
                 : "+v"(acc) : "a"(w), "v"(b))

// Row shuffle: unit j, gate q (torch order i,f,g,o = src row q*512+j):
// R = (j>>2)*16 + (j&3)*4 + q. With C/D row=(lane>>4)*4+reg: reg==gate,
// unit lane-local -> pointwise cell needs no cross-lane.
__global__ void prep_kernel(const float* __restrict__ Wih, const float* __restrict__ Whh,
                            const float* __restrict__ bih, const float* __restrict__ bhh,
                            h16* __restrict__ Wr, float* __restrict__ biasr,
                            unsigned* __restrict__ flags) {
    int idx = blockIdx.x * 256 + threadIdx.x;
    if (idx < NR_ * Kc_) {
        int R = idx / Kc_, k = idx - R * Kc_;
        int Q = R >> 4, rw = R & 15;
        int j = Q * 4 + (rw >> 2), q = rw & 3;
        int src = q * H_ + j;
        float w = (k < D_) ? Wih[src * D_ + k] : Whh[src * H_ + (k - D_)];
        Wr[idx] = (h16)w;
    }
    if (idx < NR_) {
        int Q = idx >> 4, rw = idx & 15;
        int j = Q * 4 + (rw >> 2), q = rw & 3;
        int src = q * H_ + j;
        biasr[idx] = bih[src] + bhh[src];
    }
    // re-zero flags EVERY launch (graph replay determinism)
    if (idx < 16384)
        __hip_atomic_store(flags + idx, 0u, __ATOMIC_RELAXED, AGENT_);
}

// Persistent LSTM, cooperative launch (co-residency only). Exchange through
// L3 via agent-scope relaxed ops (proven R5/R9 path, no placement assumptions).
// Block (bt=blk>>3, ht=blk&7): batch [bt*32,+32), units [ht*64,+64).
// Halves A(0-15)/B(16-31) pipelined; flag poll + h loads issued inside the
// other half's compute. W slice lives in 160 AGPRs per wave for all 256 steps;
// MFMA consumes it directly from AGPRs (gfx950 unified RF).
__global__ void __launch_bounds__(512, 2) lstm_kernel(
    const float* __restrict__ x,      // [B][T][D] fp32
    const h16*  __restrict__ Wr,      // [2048][640] fp16 (R-mapped)
    const float* __restrict__ biasr,  // [2048]
    h16* __restrict__ hbuf,           // [2][B][H] fp16 double buffer
    unsigned* __restrict__ flags)     // [32 groups][2 phases][8 prod x 32]
{
    __shared__ __align__(16) char ldsx[8192];     // [32 rows][128 k] fp16, swizzled
    __shared__ __align__(16) char ldshA[16384];   // [16 rows][512 k] fp16 half A
    __shared__ __align__(16) char ldshB[16384];
    __shared__ __align__(16) char ldsb[2048];     // bounce [16 rows][64 u] fp16

    const int blk = blockIdx.x;
    const int bt  = blk >> 3;
    const int ht  = blk & 7;
    const int tid = threadIdx.x;
    const int wv  = tid >> 6, l = tid & 63;
    const int ll  = l & 15, lh = l >> 4;
    const int Rb  = ht * 256 + wv * 32;
    const int bbase = bt * 32;

    // ---- W slice -> AGPRs (once, resident all 256 steps) ----
    half8 warr[2][20];
#pragma unroll
    for (int rt = 0; rt < 2; ++rt) {
        const h16* wbase = Wr + (size_t)(Rb + rt * 16 + ll) * Kc_ + lh * 8;
#pragma unroll
        for (int kc = 0; kc < 20; ++kc)
            warr[rt][kc] = *reinterpret_cast<const half8*>(wbase + kc * 32);
    }
#define PIN20(rt) \
    asm volatile("" : "+a"(warr[rt][0]), "+a"(warr[rt][1]), "+a"(warr[rt][2]), \
                      "+a"(warr[rt][3]), "+a"(warr[rt][4]), "+a"(warr[rt][5]), \
                      "+a"(warr[rt][6]), "+a"(warr[rt][7]), "+a"(warr[rt][8]), \
                      "+a"(warr[rt][9]), "+a"(warr[rt][10]), "+a"(warr[rt][11]), \
                      "+a"(warr[rt][12]), "+a"(warr[rt][13]), "+a"(warr[rt][14]), \
                      "+a"(warr[rt][15]), "+a"(warr[rt][16]), "+a"(warr[rt][17]), \
                      "+a"(warr[rt][18]), "+a"(warr[rt][19]))
    PIN20(0); PIN20(1);

    f32x4 bias4[2];
#pragma unroll
    for (int rt = 0; rt < 2; ++rt)
        bias4[rt] = *reinterpret_cast<const f32x4*>(biasr + Rb + rt * 16 + lh * 4);

    float cstA[2] = {0.f, 0.f}, cstB[2] = {0.f, 0.f};

    // staging ids
    const int xrow = tid >> 4, xcol = tid & 15;   // x: 32 rows x 16 cols x 32B(fp32)
    const int hrow = tid >> 5, hcol = tid & 31;   // h: 16 rows x 32 cols x 32B

    unsigned* fbase = flags + bt * 512;
    unsigned* myfA  = fbase + ht * 32;
    unsigned* myfB  = fbase + 256 + ht * 32;
    const unsigned* wfpA = fbase + (l & 7) * 32;
    const unsigned* wfpB = fbase + 256 + (l & 7) * 32;

    unsigned fv = 0;
    f32x4 xv0, xv1;
    u32x4 hv0, hv1;

    auto issueFlag = [&](const unsigned* p) {
        asm volatile("global_load_dword %0, %1, off sc0 sc1" : "=v"(fv) : "v"(p));
    };
    auto issueX = [&](int t) {
        const float* xp = x + ((size_t)(bbase + xrow) * T_ + t) * D_ + xcol * 8;
        asm volatile("global_load_dwordx4 %0, %2, off\n\t"
                     "global_load_dwordx4 %1, %2, off offset:16"
                     : "=&v"(xv0), "=&v"(xv1) : "v"(xp));
    };
    auto issueH = [&](const h16* hsrc, int rowoff) {
        const char* hp = (const char*)(hsrc + (size_t)(bbase + rowoff + hrow) * H_) + hcol * 32;
        asm volatile("global_load_dwordx4 %0, %2, off sc0 sc1\n\t"
                     "global_load_dwordx4 %1, %2, off offset:16 sc0 sc1"
                     : "=&v"(hv0), "=&v"(hv1) : "v"(hp) : "memory");
    };
    auto spinFlag = [&](unsigned tgt, const unsigned* p) {
        while (!__all(fv >= tgt)) {
            __builtin_amdgcn_s_sleep(2);
            asm volatile("global_load_dword %0, %1, off sc0 sc1\n\ts_waitcnt vmcnt(0)"
                         : "=v"(fv) : "v"(p) : "memory");
        }
    };
    auto stageX = [&]() {
        half8 r;
#pragma unroll
        for (int u = 0; u < 4; ++u) { r[u] = (h16)xv0[u]; r[4 + u] = (h16)xv1[u]; }
        *reinterpret_cast<half8*>(ldsx + ((xrow * 256 + xcol * 16) ^ ((xrow & 7) << 4))) = r;
    };
    auto stageH = [&](char* ldsh) {
        const int swz = (hrow & 7) << 4;
        const int g0 = hcol * 2, g1 = hcol * 2 + 1;
        *reinterpret_cast<u32x4*>(ldsh + ((hrow * 1024 + (g0 ^ (g0 >> 1)) * 16) ^ swz)) = hv0;
        *reinterpret_cast<u32x4*>(ldsh + ((hrow * 1024 + (g1 ^ (g1 >> 1)) * 16) ^ swz)) = hv1;
    };
    auto computeX = [&](int rowoff, f32x4* acc) {
#pragma unroll
        for (int kk = 0; kk < 4; ++kk) {
            const int row = rowoff + ll;
            half8 bf = *reinterpret_cast<const half8*>(
                ldsx + ((row * 256 + (kk * 4 + lh) * 16) ^ ((row & 7) << 4)));
            MFMA_A(acc[0], warr[0][kk], bf);
            MFMA_A(acc[1], warr[1][kk], bf);
        }
    };
    auto computeH_lo = [&](const char* ldsh, f32x4* acc) {
#pragma unroll
        for (int kk = 0; kk < 8; ++kk) {
            const int ks = kk * 4 + lh;
            half8 bf = *reinterpret_cast<const half8*>(
                ldsh + ((ll * 1024 + (ks ^ (ks >> 1)) * 16) ^ ((ll & 7) << 4)));
            MFMA_A(acc[0], warr[0][4 + kk], bf);
            MFMA_A(acc[1], warr[1][4 + kk], bf);
        }
    };
    auto computeH_hi = [&](const char* ldsh, f32x4* acc) {
#pragma unroll
        for (int kk = 8; kk < 16; ++kk) {
            const int ks = kk * 4 + lh;
            half8 bf = *reinterpret_cast<const half8*>(
                ldsh + ((ll * 1024 + (ks ^ (ks >> 1)) * 16) ^ ((ll & 7) << 4)));
            MFMA_A(acc[0], warr[0][4 + kk], bf);
            MFMA_A(acc[1], warr[1][4 + kk], bf);
        }
    };
    auto cellHalf = [&](f32x4* acc, float* cst) {
        // raw-asm MFMA bypasses the compiler's hazard logic: guard VALU reads
        // of the accumulators with wait states, ordered via the "+v" ties.
        asm volatile("s_nop 7\n\ts_nop 7" : "+v"(acc[0]), "+v"(acc[1]));
#pragma unroll
        for (int rt = 0; rt < 2; ++rt) {
            f32x4 g4 = acc[rt];
            const float gi = sigm_(g4[0]);
            const float gf = sigm_(g4[1]);
            const float gg = tanh_(g4[2]);
            const float go = sigm_(g4[3]);
            const float c  = gf * cst[rt] + gi * gg;
            cst[rt] = c;
            const float hn = go * tanh_(c);
            const int u = wv * 8 + rt * 4 + lh;
            *reinterpret_cast<h16*>(ldsb + ((ll * 128 + u * 2) ^ ((ll & 7) << 4))) = (h16)hn;
        }
    };
    auto storeHalf = [&](h16* hcur, int rowoff) {
        if (tid < 256) {
            const int r2 = tid >> 4, c2 = tid & 15;
            ull pk = *reinterpret_cast<const ull*>(
                ldsb + ((r2 * 128 + c2 * 8) ^ ((r2 & 7) << 4)));
            ull* dst = reinterpret_cast<ull*>(
                hcur + (size_t)(bbase + rowoff + r2) * H_ + ht * 64 + c2 * 4);
            __hip_atomic_store(dst, pk, __ATOMIC_RELAXED, AGENT_);
        }
    };

    // ---- prologue: zero both h tiles, load+stage x(0) ----
    {
        half8 z;
#pragma unroll
        for (int u = 0; u < 8; ++u) z[u] = (h16)0.f;
        *reinterpret_cast<half8*>(ldshA + tid * 32)      = z;
        *reinterpret_cast<half8*>(ldshA + tid * 32 + 16) = z;
        *reinterpret_cast<half8*>(ldshB + tid * 32)      = z;
        *reinterpret_cast<half8*>(ldshB + tid * 32 + 16) = z;
        issueX(0);
        asm volatile("s_waitcnt vmcnt(0)" : "+v"(xv0), "+v"(xv1) :: "memory");
        stageX();
    }
    __syncthreads();

    for (int t = 0; t < T_; ++t) {
        PIN20(0); PIN20(1);   // loop-carried: W stays in AGPRs across the loop

        h16* hcur        = hbuf + (size_t)(t & 1) * (B_ * H_);
        const h16* hprev = hbuf + (size_t)((t & 1) ^ 1) * (B_ * H_);

        // ========== phase A (rows 0-15, reads ldshA = hA(t-1)) ==========
        if (t > 0) issueFlag(wfpB);                 // oldest outstanding: flag
        issueX(t + 1 < T_ ? t + 1 : t);
        f32x4 acc[2] = {bias4[0], bias4[1]};
        computeX(0, acc);
        computeH_lo(ldshA, acc);
        if (t > 0) {
            // wait ONLY the flag (in-order vmcnt retire; x still in flight)
            asm volatile("s_waitcnt vmcnt(2)" : "+v"(fv) :: "memory");
            if (!__all(fv >= (unsigned)t)) spinFlag((unsigned)t, wfpB);
            issueH(hprev, 16);                      // hB(t-1), hides under hi+cell
        }
        computeH_hi(ldshA, acc);
        cellHalf(acc, cstA);
        __syncthreads();                            // S1
        if (t > 0) {
            asm volatile("s_waitcnt vmcnt(0)" : "+v"(hv0), "+v"(hv1) :: "memory");
            stageH(ldshB);
        }
        storeHalf(hcur, 0);                         // hA(t) -> L3
        __syncthreads();                            // S2: h stores drained
        if (tid == 0)
            __hip_atomic_store(myfA, (unsigned)(t + 1), __ATOMIC_RELAXED, AGENT_);

        // ========== phase B (rows 16-31, reads ldshB = hB(t-1)) ==========
        issueFlag(wfpA);
        f32x4 accB[2] = {bias4[0], bias4[1]};
        computeX(16, accB);
        computeH_lo(ldshB, accB);
        asm volatile("s_waitcnt vmcnt(0)" : "+v"(fv) :: "memory");
        if (!__all(fv >= (unsigned)(t + 1))) spinFlag((unsigned)(t + 1), wfpA);
        issueH(hcur, 0);                            // hA(t), hides under hi+cell
        computeH_hi(ldshB, accB);
        cellHalf(accB, cstB);
        __syncthreads();                            // S3
        asm volatile("s_waitcnt vmcnt(0)"
                     : "+v"(hv0), "+v"(hv1), "+v"(xv0), "+v"(xv1) :: "memory");
        stageH(ldshA);                              // hA(t) for step t+1
        stageX();                                   // x(t+1)
        storeHalf(hcur, 16);                        // hB(t) -> L3
        __syncthreads();                            // S4: drained
        if (tid == 0)
            __hip_atomic_store(myfB, (unsigned)(t + 1), __ATOMIC_RELAXED, AGENT_);
    }
#undef PIN20
}

// features = hT @ Wfeat^T + bfeat ; out = features @ Wout^T + bout
__global__ void __launch_bounds__(256) final_kernel(
    const h16* __restrict__ hT, const float* __restrict__ Wfeat,
    const float* __restrict__ bfeat, const float* __restrict__ Wout,
    const float* __restrict__ bout, float* __restrict__ out)
{
    __shared__ __align__(16) h16 hsh[16][512];
    __shared__ float fsh[16][256];
    const int tid = threadIdx.x;
    const int b0  = blockIdx.x * 16;

    {
        const int row = tid >> 4, seg = tid & 15;
        const half8* s8 = reinterpret_cast<const half8*>(hT + (size_t)(b0 + row) * H_ + seg * 32);
        half8* d8 = reinterpret_cast<half8*>(&hsh[row][seg * 32]);
        d8[0] = s8[0]; d8[1] = s8[1]; d8[2] = s8[2]; d8[3] = s8[3];
    }
    __syncthreads();

    float acc[16];
#pragma unroll
    for (int b = 0; b < 16; ++b) acc[b] = 0.f;
    const float* wrow = Wfeat + (size_t)tid * H_;
    for (int k8 = 0; k8 < H_ / 8; ++k8) {
        f32x4 w0 = *reinterpret_cast<const f32x4*>(wrow + k8 * 8);
        f32x4 w1 = *reinterpret_cast<const f32x4*>(wrow + k8 * 8 + 4);
#pragma unroll
        for (int b = 0; b < 16; ++b) {
            half8 h8 = *reinterpret_cast<const half8*>(&hsh[b][k8 * 8]);
#pragma unroll
            for (int u = 0; u < 4; ++u) {
                acc[b] = fmaf(w0[u], (float)h8[u], acc[b]);
                acc[b] = fmaf(w1[u], (float)h8[4 + u], acc[b]);
            }
        }
    }
    const float bf = bfeat[tid];
#pragma unroll
    for (int b = 0; b < 16; ++b) fsh[b][tid] = acc[b] + bf;
    __syncthreads();

    if (tid < 32) {
        const int b = tid >> 1, oc = tid & 1;
        float a = bout[oc];
        const float* wo = Wout + oc * 256;
        for (int f = 0; f < 256; ++f) a = fmaf(wo[f], fsh[b][f], a);
        out[(size_t)(b0 + b) * 2 + oc] = a;
    }
}

extern "C" void kernel_launch(void* const* d_in, const int* in_sizes, int n_in,
                              void* d_out, int out_size, void* d_ws, size_t ws_size,
                              hipStream_t stream) {
    const float* x     = (const float*)d_in[0];
    const float* Wih   = (const float*)d_in[1];
    const float* Whh   = (const float*)d_in[2];
    const float* bih   = (const float*)d_in[3];
    const float* bhh   = (const float*)d_in[4];
    const float* Wfeat = (const float*)d_in[5];
    const float* bfeat = (const float*)d_in[6];
    const float* Wout  = (const float*)d_in[7];
    const float* bout  = (const float*)d_in[8];
    float* out = (float*)d_out;

    char* ws = (char*)d_ws;
    h16*      Wr    = (h16*)ws;                          // 2,621,440 B
    float*    biasr = (float*)(ws + 2621440);            // 8,192 B
    h16*      hbuf  = (h16*)(ws + 2621440 + 8192);       // 2,097,152 B
    unsigned* flags = (unsigned*)(ws + 2621440 + 8192 + 2097152);  // 65,536 B

    prep_kernel<<<dim3((NR_ * Kc_ + 255) / 256), dim3(256), 0, stream>>>(
        Wih, Whh, bih, bhh, Wr, biasr, flags);

    void* args[] = {(void*)&x, (void*)&Wr, (void*)&biasr, (void*)&hbuf, (void*)&flags};
    hipLaunchCooperativeKernel((void*)lstm_kernel, dim3(256), dim3(512), args, 0, stream);

    const h16* hT = hbuf + (size_t)(B_ * H_);   // slot (T-1)&1 == 1
    final_kernel<<<dim3(B_ / 16), dim3(256), 0, stream>>>(hT, Wfeat, bfeat, Wout, bout, out);
}

// Round 11
// 1183.399 us; speedup vs baseline: 4.1466x; 4.1466x over previous
//
#include <hip/hip_runtime.h>

typedef _Float16 h16;
typedef __attribute__((ext_vector_type(8))) _Float16 half8;
typedef __attribute__((ext_vector_type(4))) float f32x4;
typedef __attribute__((ext_vector_type(4))) unsigned u32x4;
typedef unsigned long long ull;

#define B_   1024
#define T_   256
#define D_   128
#define H_   512
#define Kc_  640    // D + H
#define NR_  2048   // 4H rows, R-mapped
#define AGENT_ __HIP_MEMORY_SCOPE_AGENT

__device__ __forceinline__ float sigm_(float v) {
    return 1.0f / (1.0f + __expf(-v));
}
__device__ __forceinline__ float tanh_(float v) {
    v = fminf(15.0f, fmaxf(-15.0f, v));
    const float e = __expf(2.0f * v);
    return (e - 1.0f) / (e + 1.0f);
}

// Row shuffle: unit j, gate q (torch order i,f,g,o = src row q*512+j):
// R = (j>>2)*16 + (j&3)*4 + q. With C/D row=(lane>>4)*4+reg: reg==gate,
// unit lane-local -> pointwise cell needs no cross-lane.
__global__ void prep_kernel(const float* __restrict__ Wih, const float* __restrict__ Whh,
                            const float* __restrict__ bih, const float* __restrict__ bhh,
                            h16* __restrict__ Wr, float* __restrict__ biasr,
                            unsigned* __restrict__ flags) {
    int idx = blockIdx.x * 256 + threadIdx.x;
    if (idx < NR_ * Kc_) {
        int R = idx / Kc_, k = idx - R * Kc_;
        int Q = R >> 4, rw = R & 15;
        int j = Q * 4 + (rw >> 2), q = rw & 3;
        int src = q * H_ + j;
        float w = (k < D_) ? Wih[src * D_ + k] : Whh[src * H_ + (k - D_)];
        Wr[idx] = (h16)w;
    }
    if (idx < NR_) {
        int Q = idx >> 4, rw = idx & 15;
        int j = Q * 4 + (rw >> 2), q = rw & 3;
        int src = q * H_ + j;
        biasr[idx] = bih[src] + bhh[src];
    }
    // re-zero flags EVERY launch (graph replay determinism)
    if (idx < 16384)
        __hip_atomic_store(flags + idx, 0u, __ATOMIC_RELAXED, AGENT_);
}

// W slice loaded via volatile asm -> values are NOT rematerializable, so the
// allocator must keep them register-resident for all 256 steps (~160 VGPRs;
// launch_bounds(512,2) gives a 256-VGPR budget). 20 loads, stride 64B, one asm.
#define LOADW(dst, base) \
    asm volatile( \
        "global_load_dwordx4 %0, %20, off\n\t" \
        "global_load_dwordx4 %1, %20, off offset:64\n\t" \
        "global_load_dwordx4 %2, %20, off offset:128\n\t" \
        "global_load_dwordx4 %3, %20, off offset:192\n\t" \
        "global_load_dwordx4 %4, %20, off offset:256\n\t" \
        "global_load_dwordx4 %5, %20, off offset:320\n\t" \
        "global_load_dwordx4 %6, %20, off offset:384\n\t" \
        "global_load_dwordx4 %7, %20, off offset:448\n\t" \
        "global_load_dwordx4 %8, %20, off offset:512\n\t" \
        "global_load_dwordx4 %9, %20, off offset:576\n\t" \
        "global_load_dwordx4 %10, %20, off offset:640\n\t" \
        "global_load_dwordx4 %11, %20, off offset:704\n\t" \
        "global_load_dwordx4 %12, %20, off offset:768\n\t" \
        "global_load_dwordx4 %13, %20, off offset:832\n\t" \
        "global_load_dwordx4 %14, %20, off offset:896\n\t" \
        "global_load_dwordx4 %15, %20, off offset:960\n\t" \
        "global_load_dwordx4 %16, %20, off offset:1024\n\t" \
        "global_load_dwordx4 %17, %20, off offset:1088\n\t" \
        "global_load_dwordx4 %18, %20, off offset:1152\n\t" \
        "global_load_dwordx4 %19, %20, off offset:1216\n\t" \
        "s_waitcnt vmcnt(0)" \
        : "=&v"(dst[0]), "=&v"(dst[1]), "=&v"(dst[2]), "=&v"(dst[3]), \
          "=&v"(dst[4]), "=&v"(dst[5]), "=&v"(dst[6]), "=&v"(dst[7]), \
          "=&v"(dst[8]), "=&v"(dst[9]), "=&v"(dst[10]), "=&v"(dst[11]), \
          "=&v"(dst[12]), "=&v"(dst[13]), "=&v"(dst[14]), "=&v"(dst[15]), \
          "=&v"(dst[16]), "=&v"(dst[17]), "=&v"(dst[18]), "=&v"(dst[19]) \
        : "v"(base))

// Persistent LSTM, cooperative launch (co-residency only). Exchange through
// L3 via agent-scope relaxed ops (proven R5/R9 path, no placement assumptions).
// Block (bt=blk>>3, ht=blk&7): batch [bt*32,+32), units [ht*64,+64).
// Halves A(0-15)/B(16-31) pipelined; flag poll + h loads issued inside the
// other half's compute (split asm issue/waitcnt) so the L3 round trip hides
// under MFMA work.
__global__ void __launch_bounds__(512, 2) lstm_kernel(
    const float* __restrict__ x,      // [B][T][D] fp32
    const h16*  __restrict__ Wr,      // [2048][640] fp16 (R-mapped)
    const float* __restrict__ biasr,  // [2048]
    h16* __restrict__ hbuf,           // [2][B][H] fp16 double buffer
    unsigned* __restrict__ flags)     // [32 groups][2 phases][8 prod x 32]
{
    __shared__ __align__(16) char ldsx[8192];     // [32 rows][128 k] fp16, swizzled
    __shared__ __align__(16) char ldshA[16384];   // [16 rows][512 k] fp16 half A
    __shared__ __align__(16) char ldshB[16384];
    __shared__ __align__(16) char ldsb[2048];     // bounce [16 rows][64 u] fp16

    const int blk = blockIdx.x;
    const int bt  = blk >> 3;
    const int ht  = blk & 7;
    const int tid = threadIdx.x;
    const int wv  = tid >> 6, l = tid & 63;
    const int ll  = l & 15, lh = l >> 4;
    const int Rb  = ht * 256 + wv * 32;
    const int bbase = bt * 32;

    // ---- W slice -> registers via volatile asm (resident all 256 steps) ----
    half8 warr0[20], warr1[20];
    {
        const h16* wb0 = Wr + (size_t)(Rb + ll) * Kc_ + lh * 8;
        const h16* wb1 = Wr + (size_t)(Rb + 16 + ll) * Kc_ + lh * 8;
        LOADW(warr0, wb0);
        LOADW(warr1, wb1);
    }
    f32x4 bias4[2];
    bias4[0] = *reinterpret_cast<const f32x4*>(biasr + Rb + lh * 4);
    bias4[1] = *reinterpret_cast<const f32x4*>(biasr + Rb + 16 + lh * 4);

    float cstA[2] = {0.f, 0.f}, cstB[2] = {0.f, 0.f};

    // staging ids
    const int xrow = tid >> 4, xcol = tid & 15;   // x: 32 rows x 16 cols x 32B(fp32)
    const int hrow = tid >> 5, hcol = tid & 31;   // h: 16 rows x 32 cols x 32B

    unsigned* fbase = flags + bt * 512;
    unsigned* myfA  = fbase + ht * 32;
    unsigned* myfB  = fbase + 256 + ht * 32;
    const unsigned* wfpA = fbase + (l & 7) * 32;
    const unsigned* wfpB = fbase + 256 + (l & 7) * 32;

    unsigned fv = 0;
    f32x4 xv0, xv1;
    u32x4 hv0, hv1;

    auto issueFlag = [&](const unsigned* p) {
        asm volatile("global_load_dword %0, %1, off sc0 sc1" : "=v"(fv) : "v"(p));
    };
    auto issueX = [&](int t) {
        const float* xp = x + ((size_t)(bbase + xrow) * T_ + t) * D_ + xcol * 8;
        asm volatile("global_load_dwordx4 %0, %2, off\n\t"
                     "global_load_dwordx4 %1, %2, off offset:16"
                     : "=&v"(xv0), "=&v"(xv1) : "v"(xp));
    };
    auto issueH = [&](const h16* hsrc, int rowoff) {
        const char* hp = (const char*)(hsrc + (size_t)(bbase + rowoff + hrow) * H_) + hcol * 32;
        asm volatile("global_load_dwordx4 %0, %2, off sc0 sc1\n\t"
                     "global_load_dwordx4 %1, %2, off offset:16 sc0 sc1"
                     : "=&v"(hv0), "=&v"(hv1) : "v"(hp) : "memory");
    };
    auto spinFlag = [&](unsigned tgt, const unsigned* p) {
        while (!__all(fv >= tgt)) {
            __builtin_amdgcn_s_sleep(2);
            asm volatile("global_load_dword %0, %1, off sc0 sc1\n\ts_waitcnt vmcnt(0)"
                         : "=v"(fv) : "v"(p) : "memory");
        }
    };
    auto stageX = [&]() {
        half8 r;
#pragma unroll
        for (int u = 0; u < 4; ++u) { r[u] = (h16)xv0[u]; r[4 + u] = (h16)xv1[u]; }
        *reinterpret_cast<half8*>(ldsx + ((xrow * 256 + xcol * 16) ^ ((xrow & 7) << 4))) = r;
    };
    auto stageH = [&](char* ldsh) {
        const int swz = (hrow & 7) << 4;
        const int g0 = hcol * 2, g1 = hcol * 2 + 1;
        *reinterpret_cast<u32x4*>(ldsh + ((hrow * 1024 + (g0 ^ (g0 >> 1)) * 16) ^ swz)) = hv0;
        *reinterpret_cast<u32x4*>(ldsh + ((hrow * 1024 + (g1 ^ (g1 >> 1)) * 16) ^ swz)) = hv1;
    };
    auto computeX = [&](int rowoff, f32x4* acc) {
#pragma unroll
        for (int kk = 0; kk < 4; ++kk) {
            const int row = rowoff + ll;
            half8 bf = *reinterpret_cast<const half8*>(
                ldsx + ((row * 256 + (kk * 4 + lh) * 16) ^ ((row & 7) << 4)));
            acc[0] = __builtin_amdgcn_mfma_f32_16x16x32_f16(warr0[kk], bf, acc[0], 0, 0, 0);
            acc[1] = __builtin_amdgcn_mfma_f32_16x16x32_f16(warr1[kk], bf, acc[1], 0, 0, 0);
        }
    };
    auto computeH_lo = [&](const char* ldsh, f32x4* acc) {
#pragma unroll
        for (int kk = 0; kk < 8; ++kk) {
            const int ks = kk * 4 + lh;
            half8 bf = *reinterpret_cast<const half8*>(
                ldsh + ((ll * 1024 + (ks ^ (ks >> 1)) * 16) ^ ((ll & 7) << 4)));
            acc[0] = __builtin_amdgcn_mfma_f32_16x16x32_f16(warr0[4 + kk], bf, acc[0], 0, 0, 0);
            acc[1] = __builtin_amdgcn_mfma_f32_16x16x32_f16(warr1[4 + kk], bf, acc[1], 0, 0, 0);
        }
    };
    auto computeH_hi = [&](const char* ldsh, f32x4* acc) {
#pragma unroll
        for (int kk = 8; kk < 16; ++kk) {
            const int ks = kk * 4 + lh;
            half8 bf = *reinterpret_cast<const half8*>(
                ldsh + ((ll * 1024 + (ks ^ (ks >> 1)) * 16) ^ ((ll & 7) << 4)));
            acc[0] = __builtin_amdgcn_mfma_f32_16x16x32_f16(warr0[4 + kk], bf, acc[0], 0, 0, 0);
            acc[1] = __builtin_amdgcn_mfma_f32_16x16x32_f16(warr1[4 + kk], bf, acc[1], 0, 0, 0);
        }
    };
    auto cellHalf = [&](f32x4* acc, float* cst) {
#pragma unroll
        for (int rt = 0; rt < 2; ++rt) {
            f32x4 g4 = acc[rt];
            const float gi = sigm_(g4[0]);
            const float gf = sigm_(g4[1]);
            const float gg = tanh_(g4[2]);
            const float go = sigm_(g4[3]);
            const float c  = gf * cst[rt] + gi * gg;
            cst[rt] = c;
            const float hn = go * tanh_(c);
            const int u = wv * 8 + rt * 4 + lh;
            *reinterpret_cast<h16*>(ldsb + ((ll * 128 + u * 2) ^ ((ll & 7) << 4))) = (h16)hn;
        }
    };
    auto storeHalf = [&](h16* hcur, int rowoff) {
        if (tid < 256) {
            const int r2 = tid >> 4, c2 = tid & 15;
            ull pk = *reinterpret_cast<const ull*>(
                ldsb + ((r2 * 128 + c2 * 8) ^ ((r2 & 7) << 4)));
            ull* dst = reinterpret_cast<ull*>(
                hcur + (size_t)(bbase + rowoff + r2) * H_ + ht * 64 + c2 * 4);
            __hip_atomic_store(dst, pk, __ATOMIC_RELAXED, AGENT_);
        }
    };

    // ---- prologue: zero both h tiles, load+stage x(0) ----
    {
        half8 z;
#pragma unroll
        for (int u = 0; u < 8; ++u) z[u] = (h16)0.f;
        *reinterpret_cast<half8*>(ldshA + tid * 32)      = z;
        *reinterpret_cast<half8*>(ldshA + tid * 32 + 16) = z;
        *reinterpret_cast<half8*>(ldshB + tid * 32)      = z;
        *reinterpret_cast<half8*>(ldshB + tid * 32 + 16) = z;
        issueX(0);
        asm volatile("s_waitcnt vmcnt(0)" : "+v"(xv0), "+v"(xv1) :: "memory");
        stageX();
    }
    __syncthreads();

    for (int t = 0; t < T_; ++t) {
        h16* hcur        = hbuf + (size_t)(t & 1) * (B_ * H_);
        const h16* hprev = hbuf + (size_t)((t & 1) ^ 1) * (B_ * H_);

        // ========== phase A (rows 0-15, reads ldshA = hA(t-1)) ==========
        if (t > 0) issueFlag(wfpB);                 // oldest outstanding: flag
        issueX(t + 1 < T_ ? t + 1 : t);
        f32x4 acc[2] = {bias4[0], bias4[1]};
        computeX(0, acc);
        computeH_lo(ldshA, acc);
        if (t > 0) {
            // wait ONLY the flag (in-order vmcnt retire; x still in flight)
            asm volatile("s_waitcnt vmcnt(2)" : "+v"(fv) :: "memory");
            if (!__all(fv >= (unsigned)t)) spinFlag((unsigned)t, wfpB);
            issueH(hprev, 16);                      // hB(t-1), hides under hi+cell
        }
        computeH_hi(ldshA, acc);
        cellHalf(acc, cstA);
        __syncthreads();                            // S1
        if (t > 0) {
            asm volatile("s_waitcnt vmcnt(0)" : "+v"(hv0), "+v"(hv1) :: "memory");
            stageH(ldshB);
        }
        storeHalf(hcur, 0);                         // hA(t) -> L3
        __syncthreads();                            // S2: h stores drained
        if (tid == 0)
            __hip_atomic_store(myfA, (unsigned)(t + 1), __ATOMIC_RELAXED, AGENT_);

        // ========== phase B (rows 16-31, reads ldshB = hB(t-1)) ==========
        issueFlag(wfpA);
        f32x4 accB[2] = {bias4[0], bias4[1]};
        computeX(16, accB);
        computeH_lo(ldshB, accB);
        asm volatile("s_waitcnt vmcnt(0)" : "+v"(fv) :: "memory");
        if (!__all(fv >= (unsigned)(t + 1))) spinFlag((unsigned)(t + 1), wfpA);
        issueH(hcur, 0);                            // hA(t), hides under hi+cell
        computeH_hi(ldshB, accB);
        cellHalf(accB, cstB);
        __syncthreads();                            // S3
        asm volatile("s_waitcnt vmcnt(0)"
                     : "+v"(hv0), "+v"(hv1), "+v"(xv0), "+v"(xv1) :: "memory");
        stageH(ldshA);                              // hA(t) for step t+1
        stageX();                                   // x(t+1)
        storeHalf(hcur, 16);                        // hB(t) -> L3
        __syncthreads();                            // S4: drained
        if (tid == 0)
            __hip_atomic_store(myfB, (unsigned)(t + 1), __ATOMIC_RELAXED, AGENT_);
    }
}

// features = hT @ Wfeat^T + bfeat ; out = features @ Wout^T + bout
__global__ void __launch_bounds__(256) final_kernel(
    const h16* __restrict__ hT, const float* __restrict__ Wfeat,
    const float* __restrict__ bfeat, const float* __restrict__ Wout,
    const float* __restrict__ bout, float* __restrict__ out)
{
    __shared__ __align__(16) h16 hsh[16][512];
    __shared__ float fsh[16][256];
    const int tid = threadIdx.x;
    const int b0  = blockIdx.x * 16;

    {
        const int row = tid >> 4, seg = tid & 15;
        const half8* s8 = reinterpret_cast<const half8*>(hT + (size_t)(b0 + row) * H_ + seg * 32);
        half8* d8 = reinterpret_cast<half8*>(&hsh[row][seg * 32]);
        d8[0] = s8[0]; d8[1] = s8[1]; d8[2] = s8[2]; d8[3] = s8[3];
    }
    __syncthreads();

    float acc[16];
#pragma unroll
    for (int b = 0; b < 16; ++b) acc[b] = 0.f;
    const float* wrow = Wfeat + (size_t)tid * H_;
    for (int k8 = 0; k8 < H_ / 8; ++k8) {
        f32x4 w0 = *reinterpret_cast<const f32x4*>(wrow + k8 * 8);
        f32x4 w1 = *reinterpret_cast<const f32x4*>(wrow + k8 * 8 + 4);
#pragma unroll
        for (int b = 0; b < 16; ++b) {
            half8 h8 = *reinterpret_cast<const half8*>(&hsh[b][k8 * 8]);
#pragma unroll
            for (int u = 0; u < 4; ++u) {
                acc[b] = fmaf(w0[u], (float)h8[u], acc[b]);
                acc[b] = fmaf(w1[u], (float)h8[4 + u], acc[b]);
            }
        }
    }
    const float bf = bfeat[tid];
#pragma unroll
    for (int b = 0; b < 16; ++b) fsh[b][tid] = acc[b] + bf;
    __syncthreads();

    if (tid < 32) {
        const int b = tid >> 1, oc = tid & 1;
        float a = bout[oc];
        const float* wo = Wout + oc * 256;
        for (int f = 0; f < 256; ++f) a = fmaf(wo[f], fsh[b][f], a);
        out[(size_t)(b0 + b) * 2 + oc] = a;
    }
}

extern "C" void kernel_launch(void* const* d_in, const int* in_sizes, int n_in,
                              void* d_out, int out_size, void* d_ws, size_t ws_size,
                              hipStream_t stream) {
    const float* x     = (const float*)d_in[0];
    const float* Wih   = (const float*)d_in[1];
    const float* Whh   = (const float*)d_in[2];
    const float* bih   = (const float*)d_in[3];
    const float* bhh   = (const float*)d_in[4];
    const float* Wfeat = (const float*)d_in[5];
    const float* bfeat = (const float*)d_in[6];
    const float* Wout  = (const float*)d_in[7];
    const float* bout  = (const float*)d_in[8];
    float* out = (float*)d_out;

    char* ws = (char*)d_ws;
    h16*      Wr    = (h16*)ws;                          // 2,621,440 B
    float*    biasr = (float*)(ws + 2621440);            // 8,192 B
    h16*      hbuf  = (h16*)(ws + 2621440 + 8192);       // 2,097,152 B
    unsigned* flags = (unsigned*)(ws + 2621440 + 8192 + 2097152);  // 65,536 B

    prep_kernel<<<dim3((NR_ * Kc_ + 255) / 256), dim3(256), 0, stream>>>(
        Wih, Whh, bih, bhh, Wr, biasr, flags);

    void* args[] = {(void*)&x, (void*)&Wr, (void*)&biasr, (void*)&hbuf, (void*)&flags};
    hipLaunchCooperativeKernel((void*)lstm_kernel, dim3(256), dim3(512), args, 0, stream);

    const h16* hT = hbuf + (size_t)(B_ * H_);   // slot (T-1)&1 == 1
    final_kernel<<<dim3(B_ / 16), dim3(256), 0, stream>>>(hT, Wfeat, bfeat, Wout, bout, out);
}